// Round 3
// baseline (114.808 us; speedup 1.0000x reference)
//
#include <hip/hip_runtime.h>

#define RADIUS 5
#define WIN 9
#define BB 4
#define KK 4
#define HH 224
#define WW 224
#define HW (HH * WW)
#define PD 234                 // HH + 2*RADIUS  (padded dim)
#define PAREA (PD * PD)        // 54756
#define NBUCKET 64
#define PARTIAL_FLOATS (NBUCKET * BB * 8)   // 2048 floats = 8 KB
#define ELEMS_PER_B (HW * 81)               // 4,064,256
#define STEPS 28                            // elements per lane
#define WAVE_ELEMS (64 * STEPS)             // 1792
#define BLOCK_WAVES 4
#define BLOCK_ELEMS (BLOCK_WAVES * WAVE_ELEMS)   // 7168
#define BLOCKS_PER_B (ELEMS_PER_B / BLOCK_ELEMS) // 567 (exact)
#define TOTAL_BLOCKS (BB * BLOCKS_PER_B)         // 2268

// d_ws layout (floats):
//   [0, 2048)                      : partial buckets [bucket][b][8] (0..3 A_k, 4..7 V_k)
//   [2048, 2048 + B*PAREA*4)       : padded seg P[b][r][c][k], float4 per (r,c)

// ---------- pre-pass: zero partials + seg [B,K,H,W] -> zero-padded [B,PD,PD,K] ----------
__global__ __launch_bounds__(256) void ncuts_pad(
    const float* __restrict__ seg, float4* __restrict__ pseg, float* __restrict__ zr)
{
    const int tid = blockIdx.x * 256 + threadIdx.x;
    if (tid < PARTIAL_FLOATS) zr[tid] = 0.f;        // partial buckets
    if (tid >= BB * PAREA) return;
    const int b  = tid / PAREA;
    const int rc = tid - b * PAREA;
    const int r  = rc / PD;
    const int c  = rc - r * PD;
    const int hh = r - RADIUS;
    const int ww = c - RADIUS;
    float4 v = {0.f, 0.f, 0.f, 0.f};
    if (hh >= 0 && hh < HH && ww >= 0 && ww < WW) {
        const float* sb = seg + (size_t)b * KK * HW + hh * WW + ww;
        v.x = sb[0 * HW];
        v.y = sb[1 * HW];
        v.z = sb[2 * HW];
        v.w = sb[3 * HW];
    }
    pseg[tid] = v;
}

// ---------- main: flat (pixel, window-offset) parallelization, no LDS ----------
// element e in [0, HW*81): p = e/81 (pixel), o = e%81 (window slot, m=o/9, n=o%9)
// A_k += w[e] * seg_k(p) * pseg_k(h+m, w+n);  V_k += w[e] * seg_k(p)
__global__ __launch_bounds__(256) void ncuts_main(
    const float* __restrict__ weight,
    const float4* __restrict__ pseg,
    float* __restrict__ partial)
{
    const int lane = threadIdx.x & 63;
    const int wid  = threadIdx.x >> 6;                 // 0..3
    const int b    = blockIdx.x / BLOCKS_PER_B;        // 567 blocks per batch
    const int blkb = blockIdx.x - b * BLOCKS_PER_B;

    const unsigned wave_base = (unsigned)(blkb * BLOCK_WAVES + wid) * WAVE_ELEMS;
    const unsigned idx0 = wave_base + (unsigned)lane;

    const float*  wsrc = weight + (size_t)b * ELEMS_PER_B;
    const float4* p4   = pseg   + (size_t)b * PAREA;

    // decompose starting element
    unsigned p = idx0 / 81u;
    unsigned o = idx0 - p * 81u;
    unsigned h = p / 224u;
    unsigned w = p - h * 224u;

    float a0 = 0.f, a1 = 0.f, a2 = 0.f, a3 = 0.f;
    float v0 = 0.f, v1 = 0.f, v2 = 0.f, v3 = 0.f;

    #pragma unroll
    for (int j = 0; j < STEPS; ++j) {
        const float wv = wsrc[wave_base + j * 64 + lane];   // coalesced 256B/wave

        const unsigned m = o / 9u;          // compiler magic-div
        const unsigned n = o - m * 9u;

        const float4 sc = p4[(h + RADIUS) * PD + (w + RADIUS)];  // seg_k(p), L1
        const float4 sv = p4[(h + m) * PD + (w + n)];            // window, L1

        const float w0 = wv * sc.x;
        const float w1 = wv * sc.y;
        const float w2 = wv * sc.z;
        const float w3 = wv * sc.w;

        a0 = fmaf(w0, sv.x, a0);
        a1 = fmaf(w1, sv.y, a1);
        a2 = fmaf(w2, sv.z, a2);
        a3 = fmaf(w3, sv.w, a3);
        v0 += w0; v1 += w1; v2 += w2; v3 += w3;

        // advance element index by 64: o += 64 wraps at most once
        o += 64u;
        if (o >= 81u) {
            o -= 81u;
            ++w;
            if (w == 224u) { w = 0u; ++h; }
        }
    }

    // wave reduction of 8 partials
    float vals[8] = { a0, a1, a2, a3, v0, v1, v2, v3 };
    #pragma unroll
    for (int i = 0; i < 8; ++i) {
        float v = vals[i];
        v += __shfl_down(v, 32);
        v += __shfl_down(v, 16);
        v += __shfl_down(v, 8);
        v += __shfl_down(v, 4);
        v += __shfl_down(v, 2);
        v += __shfl_down(v, 1);
        vals[i] = v;
    }

    if (lane == 0) {
        const int bucket = (blkb + wid * 16) & (NBUCKET - 1);
        float* dst = partial + (bucket * BB + b) * 8;
        #pragma unroll
        for (int i = 0; i < 8; ++i)
            atomicAdd(dst + i, vals[i]);
    }
}

// ---------- final: fold buckets, compute loss ----------
__global__ __launch_bounds__(64) void ncuts_final(
    const float* __restrict__ partial, float* __restrict__ out)
{
    __shared__ float sums[32];
    const int t = threadIdx.x;
    if (t < 32) {
        float s = 0.f;
        for (int bucket = 0; bucket < NBUCKET; ++bucket)
            s += partial[bucket * 32 + t];
        sums[t] = s;
    }
    __syncthreads();
    if (t == 0) {
        float total = 0.f;
        for (int b = 0; b < BB; ++b) {
            float assoc = 0.f;
            for (int k = 0; k < KK; ++k) {
                const float A = sums[b * 8 + k];
                const float V = sums[b * 8 + 4 + k];
                assoc += A / V;
            }
            total += (float)KK - assoc;
        }
        out[0] = total;
    }
}

extern "C" void kernel_launch(void* const* d_in, const int* in_sizes, int n_in,
                              void* d_out, int out_size, void* d_ws, size_t ws_size,
                              hipStream_t stream) {
    const float* seg    = (const float*)d_in[0];
    const float* weight = (const float*)d_in[1];
    float* out     = (float*)d_out;
    float* wsf     = (float*)d_ws;
    float* partial = wsf;                               // 2048 floats
    float4* pseg   = (float4*)(wsf + PARTIAL_FLOATS);   // byte offset 8192, 16B aligned

    // pre-pass: zero partials + build padded seg (no separate memset dispatch)
    {
        const int total = BB * PAREA;           // 219024
        const int grid  = (total + 255) / 256;  // 856
        hipLaunchKernelGGL(ncuts_pad, dim3(grid), dim3(256), 0, stream, seg, pseg, wsf);
    }

    // main: flat element-parallel sweep over weight
    hipLaunchKernelGGL(ncuts_main, dim3(TOTAL_BLOCKS), dim3(256), 0, stream,
                       weight, pseg, partial);

    // final: fold buckets, write loss
    hipLaunchKernelGGL(ncuts_final, dim3(1), dim3(64), 0, stream, partial, out);
}

// Round 5
// 109.892 us; speedup vs baseline: 1.0447x; 1.0447x over previous
//
#include <hip/hip_runtime.h>

#define RADIUS 5
#define WIN 9
#define BB 4
#define KK 4
#define HH 224
#define WW 224
#define HW (HH * WW)
#define PD 234                 // HH + 2*RADIUS
#define PAREA (PD * PD)        // 54756
#define NBUCKET 64
#define PARTIAL_FLOATS (NBUCKET * BB * 8)   // 2048 floats = 8 KB

// ---- main-kernel tiling: 1 wave per block, 56-pixel tiles (quarter image row) ----
#define TILE_PIX 56
#define TILES_PER_B (HH * 4)               // 896 tiles per batch image
#define TOTAL_TILES (BB * TILES_PER_B)     // 3584
#define TPB 7                              // tiles per block
#define NBLK (TOTAL_TILES / TPB)           // 512 blocks = exactly 2 per CU
#define TW_FLOATS (TILE_PIX * 81)          // 4536 weight floats per tile
#define TW_BYTES (TW_FLOATS * 4)           // 18144 (16B-multiple)
#define TW_FULL_LOADS 17                   // 17*64 float4 = 1088; remainder 46
#define TW_REM 46
#define TP_BYTES (9 * 64 * 16)             // 9216: 9 rows x 64 float4
#define LDS_BYTES (2 * TW_BYTES + 2 * TP_BYTES)  // 54720 < 64KB

// d_ws layout (floats):
//   [0, 2048)                      : partial buckets [bucket][b][8] (0..3 A_k, 4..7 V_k)
//   [2048, 2048 + B*PAREA*4)       : padded seg P[b][r][c][k], float4 per (r,c)

// ---------- pre-pass: zero partials + seg [B,K,H,W] -> zero-padded [B,PD,PD,K] ----------
__global__ __launch_bounds__(256) void ncuts_pad(
    const float* __restrict__ seg, float4* __restrict__ pseg, float* __restrict__ zr)
{
    const int tid = blockIdx.x * 256 + threadIdx.x;
    if (tid < PARTIAL_FLOATS) zr[tid] = 0.f;        // partial buckets
    if (tid >= BB * PAREA) return;
    const int b  = tid / PAREA;
    const int rc = tid - b * PAREA;
    const int r  = rc / PD;
    const int c  = rc - r * PD;
    const int hh = r - RADIUS;
    const int ww = c - RADIUS;
    float4 v = {0.f, 0.f, 0.f, 0.f};
    if (hh >= 0 && hh < HH && ww >= 0 && ww < WW) {
        const float* sb = seg + (size_t)b * KK * HW + hh * WW + ww;
        v.x = sb[0 * HW];
        v.y = sb[1 * HW];
        v.z = sb[2 * HW];
        v.w = sb[3 * HW];
    }
    pseg[tid] = v;
}

// ---------- main: 1 wave/block, double-buffered LDS (weights + pseg rows), counted vmcnt ----------
__global__ __launch_bounds__(64) void ncuts_main(
    const float* __restrict__ weight,
    const float4* __restrict__ pseg,
    float* __restrict__ partial)
{
    __shared__ char lds[LDS_BYTES];

    const int lane = threadIdx.x;          // 0..63
    const int blk  = blockIdx.x;
    const int t0   = blk * TPB;            // first tile of this block
    const int b    = t0 / TILES_PER_B;     // uniform per block (896 = 7*128)
    const float4* p4 = pseg + (size_t)b * PAREA;

    // ---- staging helpers (wave-uniform LDS base + lane*16 hardware layout) ----
    auto stage_w = [&](int t, int s) {
        const float4* src = (const float4*)(weight + (size_t)t * TW_FLOATS);
        char* dst = lds + s * TW_BYTES;
        #pragma unroll
        for (int j = 0; j < TW_FULL_LOADS; ++j)
            __builtin_amdgcn_global_load_lds(
                (__attribute__((address_space(1))) void*)(src + j * 64 + lane),
                (__attribute__((address_space(3))) void*)(dst + j * 1024),
                16, 0, 0);
        if (lane < TW_REM)
            __builtin_amdgcn_global_load_lds(
                (__attribute__((address_space(1))) void*)(src + TW_FULL_LOADS * 64 + lane),
                (__attribute__((address_space(3))) void*)(dst + TW_FULL_LOADS * 1024),
                16, 0, 0);
    };
    auto stage_p = [&](int t, int s) {
        const int r  = t - b * TILES_PER_B;
        const int h  = r >> 2;
        const int w0 = (r & 3) * TILE_PIX;
        const float4* src = p4 + h * PD + w0;
        char* dst = lds + 2 * TW_BYTES + s * TP_BYTES;
        #pragma unroll
        for (int rr = 0; rr < 9; ++rr)
            __builtin_amdgcn_global_load_lds(
                (__attribute__((address_space(1))) void*)(src + rr * PD + lane),
                (__attribute__((address_space(3))) void*)(dst + rr * 1024),
                16, 0, 0);
    };

    // ---- prologue: prefetch tiles 0 and 1 (FIFO: W0(18) P0(9) W1(18) P1(9)) ----
    stage_w(t0 + 0, 0);
    stage_p(t0 + 0, 0);
    stage_w(t0 + 1, 1);
    stage_p(t0 + 1, 1);

    float accA0 = 0.f, accA1 = 0.f, accA2 = 0.f, accA3 = 0.f;
    float accV0 = 0.f, accV1 = 0.f, accV2 = 0.f, accV3 = 0.f;

    for (int i = 0; i < TPB; ++i) {
        // wait for tile i's 27 DMA ops; leave tile i+1's 27 in flight (never drain to 0 mid-loop)
        if (i < TPB - 1) asm volatile("s_waitcnt vmcnt(27)" ::: "memory");
        else             asm volatile("s_waitcnt vmcnt(0)"  ::: "memory");
        __builtin_amdgcn_sched_barrier(0);

        const int s = i & 1;
        const float*  wl = (const float*)(lds + s * TW_BYTES) + lane * 81;
        const float4* pl = (const float4*)(lds + 2 * TW_BYTES + s * TP_BYTES) + lane;

        if (lane < TILE_PIX) {
            float a0 = 0.f, a1 = 0.f, a2 = 0.f, a3 = 0.f, ws = 0.f;
            #pragma unroll
            for (int m = 0; m < WIN; ++m) {
                #pragma unroll
                for (int n = 0; n < WIN; ++n) {
                    const float  wv = wl[m * WIN + n];          // ds_read_b32, imm offset
                    const float4 sv = pl[m * 64 + n];           // ds_read_b128, imm offset
                    a0 = fmaf(wv, sv.x, a0);
                    a1 = fmaf(wv, sv.y, a1);
                    a2 = fmaf(wv, sv.z, a2);
                    a3 = fmaf(wv, sv.w, a3);
                    ws += wv;
                }
            }
            const float4 sc = pl[5 * 64 + 5];                   // seg_k at center pixel
            accA0 = fmaf(a0, sc.x, accA0);
            accA1 = fmaf(a1, sc.y, accA1);
            accA2 = fmaf(a2, sc.z, accA2);
            accA3 = fmaf(a3, sc.w, accA3);
            accV0 = fmaf(ws, sc.x, accV0);
            accV1 = fmaf(ws, sc.y, accV1);
            accV2 = fmaf(ws, sc.z, accV2);
            accV3 = fmaf(ws, sc.w, accV3);
        }

        if (i + 2 < TPB) {
            __builtin_amdgcn_sched_barrier(0);
            asm volatile("s_waitcnt lgkmcnt(0)" ::: "memory");  // ds_reads of buffer s drained
            __builtin_amdgcn_sched_barrier(0);
            stage_w(t0 + i + 2, s);                              // refill freed buffers
            stage_p(t0 + i + 2, s);
        }
    }

    // ---- block-level reduction: one atomic set per block ----
    float vals[8] = { accA0, accA1, accA2, accA3, accV0, accV1, accV2, accV3 };
    #pragma unroll
    for (int i = 0; i < 8; ++i) {
        float v = vals[i];
        v += __shfl_down(v, 32);
        v += __shfl_down(v, 16);
        v += __shfl_down(v, 8);
        v += __shfl_down(v, 4);
        v += __shfl_down(v, 2);
        v += __shfl_down(v, 1);
        vals[i] = v;
    }
    if (lane == 0) {
        const int bucket = blk & (NBUCKET - 1);
        float* dst = partial + (bucket * BB + b) * 8;
        #pragma unroll
        for (int i = 0; i < 8; ++i)
            atomicAdd(dst + i, vals[i]);
    }
}

// ---------- final: fold buckets, compute loss ----------
__global__ __launch_bounds__(64) void ncuts_final(
    const float* __restrict__ partial, float* __restrict__ out)
{
    __shared__ float sums[32];
    const int t = threadIdx.x;
    if (t < 32) {
        float s = 0.f;
        for (int bucket = 0; bucket < NBUCKET; ++bucket)
            s += partial[bucket * 32 + t];
        sums[t] = s;
    }
    __syncthreads();
    if (t == 0) {
        float total = 0.f;
        for (int b = 0; b < BB; ++b) {
            float assoc = 0.f;
            for (int k = 0; k < KK; ++k) {
                const float A = sums[b * 8 + k];
                const float V = sums[b * 8 + 4 + k];
                assoc += A / V;
            }
            total += (float)KK - assoc;
        }
        out[0] = total;
    }
}

extern "C" void kernel_launch(void* const* d_in, const int* in_sizes, int n_in,
                              void* d_out, int out_size, void* d_ws, size_t ws_size,
                              hipStream_t stream) {
    const float* seg    = (const float*)d_in[0];
    const float* weight = (const float*)d_in[1];
    float* out     = (float*)d_out;
    float* wsf     = (float*)d_ws;
    float* partial = wsf;                               // 2048 floats
    float4* pseg   = (float4*)(wsf + PARTIAL_FLOATS);   // byte offset 8192, 16B aligned

    // pre-pass: zero partials + build padded seg (no separate memset dispatch)
    {
        const int total = BB * PAREA;           // 219024
        const int grid  = (total + 255) / 256;  // 856
        hipLaunchKernelGGL(ncuts_pad, dim3(grid), dim3(256), 0, stream, seg, pseg, wsf);
    }

    // main: persistent 512 one-wave blocks, double-buffered LDS pipeline
    hipLaunchKernelGGL(ncuts_main, dim3(NBLK), dim3(64), 0, stream,
                       weight, pseg, partial);

    // final: fold buckets, write loss
    hipLaunchKernelGGL(ncuts_final, dim3(1), dim3(64), 0, stream, partial, out);
}